// Round 1
// 1587.448 us; speedup vs baseline: 1.6313x; 1.6313x over previous
//
#include <hip/hip_runtime.h>

// Problem: B=8, H=16, S=1024, D=64, fp32.
// d_out = context[B,H,S,D] (8,388,608 f32) ++ attn[B,H,S,S] (134,217,728 f32).
#define S_ 1024
#define D_ 64
#define CTX_ELEMS (8 * 16 * 1024 * 64)

// ---------------------------------------------------------------------------
// Mask dtype detector: scans first 1024 32-bit words of the mask buffer.
//   int32 mask  -> words in {0,1}            -> mode 0
//   uint8 mask  -> words with bytes {0,1}    -> some word > 1        -> bit0
//   float mask  -> words 0x00000000/0x3F800000 -> bit1
// Writes mode flag to d_ws[0]. Runs every launch (d_ws is re-poisoned).
// ---------------------------------------------------------------------------
__global__ void detect_mask_kernel(const unsigned int* __restrict__ mask,
                                   int* __restrict__ flag) {
  const int t = threadIdx.x;
  if (t == 0) flag[0] = 0;
  __syncthreads();
  unsigned int local = 0;
  for (int i = t; i < 1024; i += 256) {
    unsigned int w = mask[i];
    if (w == 0x3F800000u)      local |= 2u;   // float 1.0 pattern
    else if (w > 1u)           local |= 1u;   // packed-byte pattern
  }
  if (local) atomicOr(flag, (int)local);
}

// ---------------------------------------------------------------------------
// Fused attention: one 256-thread block per (bh, 16-query tile).
// Phase 1 (QK^T): threads = 4 q-groups(waves) x 64 k-lanes; acc[4][16] holds
//   the full 16x1024 score tile in registers (k = 64*ci + kl).
// Softmax: per-wave __shfl_xor reductions (all lanes of a wave share q-group).
// Phase 2 (PV): attn chunks round-trip through LDS to a (q, d4) thread layout;
//   context accumulates in a float4 per thread, no cross-lane reduction.
//
// R1 FIX: the kt/vt tile loops were NOT unrolled, so acc[qq][2*kt] was
// runtime-indexed -> LLVM demoted acc[4][16] to scratch (VGPR_Count was 68,
// i.e. < the 64 accumulators; WRITE_SIZE showed 2.1 GB of scratch stores).
// Fully unrolling kt and vt makes every acc index a compile-time constant so
// the array lives in VGPRs. __launch_bounds__(256,2) gives the allocator a
// 256-VGPR budget (LDS already caps occupancy at 3 blocks/CU, so the extra
// registers are free).
// ---------------------------------------------------------------------------
__global__ __launch_bounds__(256, 2)
void attn_fused_kernel(const float* __restrict__ Q, const float* __restrict__ K,
                       const float* __restrict__ V, const void* __restrict__ mask,
                       float* __restrict__ out, const int* __restrict__ flag) {
  // LDS: stride 17 float4 (=68 floats): 2-way bank aliasing only (free).
  __shared__ float4 Qs[16][17];     //  4.25 KB
  __shared__ float4 KVs[128][17];   // 34.8 KB (K tiles, then V tiles)
  __shared__ float  As[16][132];    //  8.25 KB (attn chunk for PV relayout)

  const int t  = threadIdx.x;
  const int qt = blockIdx.x;        // 0..63  (query tile)
  const int bh = blockIdx.y;        // 0..127 (b*H+h)
  const int q0 = qt * 16;

  const int qg = t >> 6;            // wave id = q-group (4 rows each)
  const int kl = t & 63;            // k lane

  const float* Qb = Q + (size_t)bh * (S_ * D_) + (size_t)q0 * D_;
  const float* Kb = K + (size_t)bh * (S_ * D_);
  const float* Vb = V + (size_t)bh * (S_ * D_);

  // ---- load Q tile (16x64 f32 = 256 float4, 1/thread, coalesced) ----
  {
    const int r = t >> 4, c = t & 15;
    Qs[r][c] = ((const float4*)Qb)[r * 16 + c];
  }

  float acc[4][16];
#pragma unroll
  for (int qq = 0; qq < 4; ++qq)
#pragma unroll
    for (int ci = 0; ci < 16; ++ci) acc[qq][ci] = 0.f;

  // ---- Phase 1: scores = Q K^T, K staged in 128-row LDS tiles ----
#pragma unroll
  for (int kt = 0; kt < 8; ++kt) {   // R1: unrolled -> acc indices constant
    __syncthreads();
#pragma unroll
    for (int i = 0; i < 8; ++i) {            // 2048 float4 per tile, 8/thread
      const int fi = t + 256 * i;
      KVs[fi >> 4][fi & 15] = ((const float4*)Kb)[kt * 2048 + fi];
    }
    __syncthreads();
#pragma unroll
    for (int d4 = 0; d4 < 16; ++d4) {
      const float4 kv0 = KVs[kl][d4];        // k_local = kl      (ci = 2kt)
      const float4 kv1 = KVs[kl + 64][d4];   // k_local = kl + 64 (ci = 2kt+1)
#pragma unroll
      for (int qq = 0; qq < 4; ++qq) {
        const float4 qv = Qs[4 * qg + qq][d4];   // wave-broadcast
        acc[qq][2 * kt]     += qv.x * kv0.x + qv.y * kv0.y + qv.z * kv0.z + qv.w * kv0.w;
        acc[qq][2 * kt + 1] += qv.x * kv1.x + qv.y * kv1.y + qv.z * kv1.z + qv.w * kv1.w;
      }
    }
  }

  // ---- mask + scale (mode branch is wave-uniform; k = 64*ci + kl) ----
  const float scale = 0.125f;                     // 1/sqrt(64)
  const int mode = *flag;
  const size_t mbase = (size_t)bh * ((size_t)S_ * S_) + (size_t)q0 * S_;
  if (mode & 2) {                                 // float32 mask
    const float* mf = (const float*)mask + mbase;
#pragma unroll
    for (int qq = 0; qq < 4; ++qq) {
      const float* mr = mf + (4 * qg + qq) * S_ + kl;
#pragma unroll
      for (int ci = 0; ci < 16; ++ci)
        acc[qq][ci] = (mr[64 * ci] != 0.f) ? -1e9f : acc[qq][ci] * scale;
    }
  } else if (mode & 1) {                          // uint8 mask
    const unsigned char* mu = (const unsigned char*)mask + mbase;
#pragma unroll
    for (int qq = 0; qq < 4; ++qq) {
      const unsigned char* mr = mu + (4 * qg + qq) * S_ + kl;
#pragma unroll
      for (int ci = 0; ci < 16; ++ci)
        acc[qq][ci] = mr[64 * ci] ? -1e9f : acc[qq][ci] * scale;
    }
  } else {                                        // int32 mask
    const int* mi = (const int*)mask + mbase;
#pragma unroll
    for (int qq = 0; qq < 4; ++qq) {
      const int* mr = mi + (4 * qg + qq) * S_ + kl;
#pragma unroll
      for (int ci = 0; ci < 16; ++ci)
        acc[qq][ci] = mr[64 * ci] ? -1e9f : acc[qq][ci] * scale;
    }
  }

  // ---- softmax per row: full-wave shuffle reductions ----
  float* outAttn = out + CTX_ELEMS;
#pragma unroll
  for (int qq = 0; qq < 4; ++qq) {
    float mx = -3.4e38f;
#pragma unroll
    for (int ci = 0; ci < 16; ++ci) mx = fmaxf(mx, acc[qq][ci]);
#pragma unroll
    for (int off = 32; off > 0; off >>= 1) mx = fmaxf(mx, __shfl_xor(mx, off, 64));
    float sum = 0.f;
#pragma unroll
    for (int ci = 0; ci < 16; ++ci) {
      const float p = __expf(acc[qq][ci] - mx);   // all-masked row -> exp(0)=1 -> uniform, matches ref
      acc[qq][ci] = p;
      sum += p;
    }
#pragma unroll
    for (int off = 32; off > 0; off >>= 1) sum += __shfl_xor(sum, off, 64);
    const float inv = 1.0f / sum;
#pragma unroll
    for (int ci = 0; ci < 16; ++ci) acc[qq][ci] *= inv;
    // write attn row slice: 64 consecutive lanes -> 256B coalesced stores
    float* ar = outAttn + mbase + (size_t)(4 * qg + qq) * S_ + kl;
#pragma unroll
    for (int ci = 0; ci < 16; ++ci) ar[64 * ci] = acc[qq][ci];
  }

  // ---- Phase 2: context = attn @ V ----
  const int qB = t >> 4, d4B = t & 15;   // relayout: thread owns (row qB, 4 d-cols)
  float4 c4 = {0.f, 0.f, 0.f, 0.f};
#pragma unroll
  for (int vt = 0; vt < 8; ++vt) {       // R1: unrolled -> acc indices constant
    __syncthreads();                      // previous tile fully consumed
#pragma unroll
    for (int i = 0; i < 8; ++i) {
      const int fi = t + 256 * i;
      KVs[fi >> 4][fi & 15] = ((const float4*)Vb)[vt * 2048 + fi];
    }
#pragma unroll
    for (int qq = 0; qq < 4; ++qq) {      // dump attn chunk (k in this tile)
      As[4 * qg + qq][kl]      = acc[qq][2 * vt];
      As[4 * qg + qq][kl + 64] = acc[qq][2 * vt + 1];
    }
    __syncthreads();
#pragma unroll 16
    for (int k_local = 0; k_local < 128; ++k_local) {
      const float  a  = As[qB][k_local];  // broadcast within 16-lane q-group
      const float4 vv = KVs[k_local][d4B];
      c4.x += a * vv.x; c4.y += a * vv.y; c4.z += a * vv.z; c4.w += a * vv.w;
    }
  }
  // context write: lanes 0..15 -> consecutive float4 (256B coalesced)
  ((float4*)(out + (size_t)bh * (S_ * D_) + (size_t)(q0 + qB) * D_))[d4B] = c4;
}

extern "C" void kernel_launch(void* const* d_in, const int* in_sizes, int n_in,
                              void* d_out, int out_size, void* d_ws, size_t ws_size,
                              hipStream_t stream) {
  const float* Q = (const float*)d_in[0];
  const float* K = (const float*)d_in[1];
  const float* V = (const float*)d_in[2];
  const void* mask = d_in[3];
  int* flag = (int*)d_ws;

  detect_mask_kernel<<<1, 256, 0, stream>>>((const unsigned int*)mask, flag);

  dim3 grid(S_ / 16, 8 * 16);   // (query tiles, B*H)
  attn_fused_kernel<<<grid, 256, 0, stream>>>(Q, K, V, mask, (float*)d_out, flag);
}